// Round 3
// baseline (155.269 us; speedup 1.0000x reference)
//
#include <hip/hip_runtime.h>
#include <math.h>

// LayerStatistics: out = (x copy [N floats], stats[5] = mean, sqmean, var(ddof=1), min, max)
// x: (32,64,128,128) fp32, N = 33554432. Single fused kernel, fence-free
// cross-block combine via device-scope atomics (fixed-point sums + monotonic
// uint keys for min/max). No __threadfence (agent-scope fence = L2 writeback
// on gfx950 = catastrophic; round-2 lesson).

constexpr int BLOCK = 256;
constexpr int GRID  = 2048;   // 2048 wg * 4 waves = 32 waves/CU

typedef float v4f __attribute__((ext_vector_type(4)));

#define QSCALE 16777216.0   // 2^24 fixed-point scale for sum / sumsq

// ws layout (all zero-initialized by a 32-byte memset each call):
//   u64 cell[0] : sum   (two's-complement fixed-point)
//   u64 cell[1] : sumsq (fixed-point)
//   u32 k[4]    : max key   (atomicMax over fkey)
//   u32 k[5]    : min key   (atomicMax over ~fkey)
//   u32 k[6]    : block-done counter

__device__ inline unsigned int fkey(float f) {
    unsigned int b = __float_as_uint(f);
    return (b & 0x80000000u) ? ~b : (b | 0x80000000u);   // monotonic total order
}
__device__ inline float fdec(unsigned int u) {
    unsigned int b = (u & 0x80000000u) ? (u & 0x7fffffffu) : ~u;
    return __uint_as_float(b);
}

__global__ __launch_bounds__(BLOCK) void stats_fused(
    const v4f* __restrict__ in, v4f* __restrict__ out,
    unsigned long long* __restrict__ cells,   // [0]=sum_q [1]=ss_q
    float* __restrict__ stats_out, int n4, double n_total)
{
    unsigned int* keys = (unsigned int*)(cells + 2);  // [0]=maxk [1]=mink [2]=counter

    const int tid    = blockIdx.x * blockDim.x + threadIdx.x;
    const int stride = gridDim.x * blockDim.x;

    float s  = 0.0f;
    float ss = 0.0f;
    float mn =  INFINITY;
    float mx = -INFINITY;

    for (int i = tid; i < n4; i += stride) {
        v4f v = in[i];
        out[i] = v;
        float a0 = v[0], a1 = v[1], a2 = v[2], a3 = v[3];
        s  += (a0 + a1) + (a2 + a3);
        ss += (a0 * a0 + a1 * a1) + (a2 * a2 + a3 * a3);
        mn = fminf(mn, fminf(fminf(a0, a1), fminf(a2, a3)));
        mx = fmaxf(mx, fmaxf(fmaxf(a0, a1), fmaxf(a2, a3)));
    }

    // wave (64-lane) reduce
    #pragma unroll
    for (int off = 32; off > 0; off >>= 1) {
        s  += __shfl_down(s,  off, 64);
        ss += __shfl_down(ss, off, 64);
        mn = fminf(mn, __shfl_down(mn, off, 64));
        mx = fmaxf(mx, __shfl_down(mx, off, 64));
    }

    __shared__ float4 red[BLOCK / 64];
    const int lane = threadIdx.x & 63;
    const int wave = threadIdx.x >> 6;
    if (lane == 0) red[wave] = make_float4(s, ss, mn, mx);
    __syncthreads();

    if (threadIdx.x != 0) return;

    float4 a = red[0];
    #pragma unroll
    for (int w = 1; w < BLOCK / 64; ++w) {
        float4 b = red[w];
        a.x += b.x;
        a.y += b.y;
        a.z = fminf(a.z, b.z);
        a.w = fmaxf(a.w, b.w);
    }

    // device-scope relaxed atomics: coherent at the common point, no cache flush
    atomicAdd(&cells[0], (unsigned long long)(long long)llrint((double)a.x * QSCALE));
    atomicAdd(&cells[1], (unsigned long long)(long long)llrint((double)a.y * QSCALE));
    atomicMax(&keys[0], fkey(a.w));    // max
    atomicMax(&keys[1], ~fkey(a.z));   // min (inverted key)

    // ensure the stat RMWs have completed at the coherence point before
    // signalling done (no release fence -> no L2 writeback)
    asm volatile("s_waitcnt vmcnt(0)" ::: "memory");

    unsigned int prev = atomicAdd(&keys[2], 1u);
    if (prev != (unsigned int)gridDim.x - 1u) return;

    // last block: all 2048 contributions are at the coherence point.
    // Read with agent-scope atomic loads (bypass potentially-stale L1/L2).
    unsigned long long sq  = __hip_atomic_load(&cells[0], __ATOMIC_RELAXED, __HIP_MEMORY_SCOPE_AGENT);
    unsigned long long ssq = __hip_atomic_load(&cells[1], __ATOMIC_RELAXED, __HIP_MEMORY_SCOPE_AGENT);
    unsigned int mk  = __hip_atomic_load(&keys[0], __ATOMIC_RELAXED, __HIP_MEMORY_SCOPE_AGENT);
    unsigned int nk  = __hip_atomic_load(&keys[1], __ATOMIC_RELAXED, __HIP_MEMORY_SCOPE_AGENT);

    double ds  = (double)(long long)sq  / QSCALE;
    double dss = (double)(long long)ssq / QSCALE;
    double mean   = ds / n_total;
    double sqmean = dss / n_total;
    double var    = (dss - ds * ds / n_total) / (n_total - 1.0);
    stats_out[0] = (float)mean;
    stats_out[1] = (float)sqmean;
    stats_out[2] = (float)var;
    stats_out[3] = fdec(~nk);
    stats_out[4] = fdec(mk);
}

extern "C" void kernel_launch(void* const* d_in, const int* in_sizes, int n_in,
                              void* d_out, int out_size, void* d_ws, size_t ws_size,
                              hipStream_t stream) {
    const float* x  = (const float*)d_in[0];
    float* out      = (float*)d_out;
    int n  = in_sizes[0];          // 33554432
    int n4 = n / 4;                // 8388608

    unsigned long long* cells = (unsigned long long*)d_ws;

    hipMemsetAsync(cells, 0, 32, stream);   // sums, keys, counter = 0
    stats_fused<<<GRID, BLOCK, 0, stream>>>((const v4f*)x, (v4f*)out,
                                            cells, out + n, n4, (double)n);
}

// Round 4
// 50.784 us; speedup vs baseline: 3.0575x; 3.0575x over previous
//
#include <hip/hip_runtime.h>
#include <math.h>

// LayerStatistics: out = (x copy [N floats], stats[5] = mean, sqmean, var(ddof=1), min, max)
// x: (32,64,128,128) fp32, N = 33554432.
// Two-dispatch structure (round-1 skeleton — single-kernel atomic rendezvous
// measured 2-3x slower on gfx950: same-address device atomics serialize at the
// cross-XCD coherence point). Pass1: fused copy+partial-reduce, nontemporal
// stores (keep x L3-resident), 4x independent-load unroll. Pass2: 1 block.

constexpr int BLOCK = 256;
constexpr int GRID  = 2048;   // 256 CU * 8 blocks/CU = 32 waves/CU

typedef float v4f __attribute__((ext_vector_type(4)));

__global__ __launch_bounds__(BLOCK) void stats_pass1(const v4f* __restrict__ in,
                                                     v4f* __restrict__ out,
                                                     float4* __restrict__ partials,
                                                     int n4) {
    const int tid    = blockIdx.x * blockDim.x + threadIdx.x;
    const int stride = gridDim.x * blockDim.x;

    float s  = 0.0f;
    float ss = 0.0f;
    float mn =  INFINITY;
    float mx = -INFINITY;

    if ((n4 & (4 * stride - 1)) == 0) {
        // fast path: 4 independent loads in flight per iteration
        for (int i = tid; i < n4; i += 4 * stride) {
            v4f v0 = in[i];
            v4f v1 = in[i + stride];
            v4f v2 = in[i + 2 * stride];
            v4f v3 = in[i + 3 * stride];
            __builtin_nontemporal_store(v0, &out[i]);
            __builtin_nontemporal_store(v1, &out[i + stride]);
            __builtin_nontemporal_store(v2, &out[i + 2 * stride]);
            __builtin_nontemporal_store(v3, &out[i + 3 * stride]);
            #pragma unroll
            for (int e = 0; e < 4; ++e) {
                float a0 = v0[e], a1 = v1[e], a2 = v2[e], a3 = v3[e];
                s  += (a0 + a1) + (a2 + a3);
                ss += (a0 * a0 + a1 * a1) + (a2 * a2 + a3 * a3);
                mn = fminf(mn, fminf(fminf(a0, a1), fminf(a2, a3)));
                mx = fmaxf(mx, fmaxf(fmaxf(a0, a1), fmaxf(a2, a3)));
            }
        }
    } else {
        for (int i = tid; i < n4; i += stride) {
            v4f v = in[i];
            __builtin_nontemporal_store(v, &out[i]);
            #pragma unroll
            for (int e = 0; e < 4; ++e) {
                float a = v[e];
                s  += a;
                ss += a * a;
                mn = fminf(mn, a);
                mx = fmaxf(mx, a);
            }
        }
    }

    // wave (64-lane) reduce
    #pragma unroll
    for (int off = 32; off > 0; off >>= 1) {
        s  += __shfl_down(s,  off, 64);
        ss += __shfl_down(ss, off, 64);
        mn = fminf(mn, __shfl_down(mn, off, 64));
        mx = fmaxf(mx, __shfl_down(mx, off, 64));
    }

    __shared__ float4 red[BLOCK / 64];
    const int lane = threadIdx.x & 63;
    const int wave = threadIdx.x >> 6;
    if (lane == 0) red[wave] = make_float4(s, ss, mn, mx);
    __syncthreads();

    if (threadIdx.x == 0) {
        float4 a = red[0];
        #pragma unroll
        for (int w = 1; w < BLOCK / 64; ++w) {
            float4 b = red[w];
            a.x += b.x;
            a.y += b.y;
            a.z = fminf(a.z, b.z);
            a.w = fmaxf(a.w, b.w);
        }
        partials[blockIdx.x] = a;
    }
}

// Pass 2: single block reduces GRID partials; double accumulation for sum/sumsq.
__global__ __launch_bounds__(BLOCK) void stats_pass2(const float4* __restrict__ partials,
                                                     float* __restrict__ stats_out,
                                                     int nparts, double n_total) {
    double s  = 0.0;
    double ss = 0.0;
    float  mn =  INFINITY;
    float  mx = -INFINITY;

    for (int i = threadIdx.x; i < nparts; i += blockDim.x) {
        float4 p = partials[i];
        s  += (double)p.x;
        ss += (double)p.y;
        mn = fminf(mn, p.z);
        mx = fmaxf(mx, p.w);
    }

    #pragma unroll
    for (int off = 32; off > 0; off >>= 1) {
        s  += __shfl_down(s,  off, 64);
        ss += __shfl_down(ss, off, 64);
        mn = fminf(mn, __shfl_down(mn, off, 64));
        mx = fmaxf(mx, __shfl_down(mx, off, 64));
    }

    __shared__ double sred[BLOCK / 64];
    __shared__ double ssred[BLOCK / 64];
    __shared__ float  mnred[BLOCK / 64];
    __shared__ float  mxred[BLOCK / 64];
    int lane = threadIdx.x & 63;
    int wave = threadIdx.x >> 6;
    if (lane == 0) { sred[wave] = s; ssred[wave] = ss; mnred[wave] = mn; mxred[wave] = mx; }
    __syncthreads();

    if (threadIdx.x == 0) {
        #pragma unroll
        for (int w = 1; w < BLOCK / 64; ++w) {
            s  += sred[w];
            ss += ssred[w];
            mn = fminf(mn, mnred[w]);
            mx = fmaxf(mx, mxred[w]);
        }
        double mean   = s / n_total;
        double sqmean = ss / n_total;
        double var    = (ss - s * s / n_total) / (n_total - 1.0);
        stats_out[0] = (float)mean;
        stats_out[1] = (float)sqmean;
        stats_out[2] = (float)var;
        stats_out[3] = mn;
        stats_out[4] = mx;
    }
}

extern "C" void kernel_launch(void* const* d_in, const int* in_sizes, int n_in,
                              void* d_out, int out_size, void* d_ws, size_t ws_size,
                              hipStream_t stream) {
    const float* x  = (const float*)d_in[0];
    float* out      = (float*)d_out;
    int n  = in_sizes[0];          // 33554432
    int n4 = n / 4;                // 8388608

    float4* partials = (float4*)d_ws;   // GRID * 16 B = 32 KiB

    stats_pass1<<<GRID, BLOCK, 0, stream>>>((const v4f*)x, (v4f*)out, partials, n4);
    stats_pass2<<<1, BLOCK, 0, stream>>>(partials, out + n, GRID, (double)n);
}